// Round 5
// baseline (379.093 us; speedup 1.0000x reference)
//
#include <hip/hip_runtime.h>
#include <hip/hip_bf16.h>

#define DEVINL __device__ __forceinline__

typedef __attribute__((ext_vector_type(8))) short bf16x8;  // 8 bf16 (4 VGPR)
typedef __attribute__((ext_vector_type(4))) float f32x4;   // MFMA 16x16 accumulator

union U8 {
    bf16x8 v;
    uint4 u;
};

DEVINL int clampidx(int v, int n) { return ((unsigned)v < (unsigned)n) ? v : 0; }
DEVINL float bflo(unsigned int u) { return __uint_as_float(u << 16); }
DEVINL float bfhi(unsigned int u) { return __uint_as_float(u & 0xffff0000u); }
// f32 -> bf16 round-to-nearest-even (finite inputs only)
DEVINL unsigned int f2bf(float f) {
    unsigned int u = __float_as_uint(f);
    u += 0x7fffu + ((u >> 16) & 1u);
    return u >> 16;
}

// split 8 f32 into bf16-hi frag + bf16-lo frag (lo = exact residual, RTN)
DEVINL void split8(const float4 v0, const float4 v1, uint4& hi, uint4& lo) {
    const float xv[8] = {v0.x, v0.y, v0.z, v0.w, v1.x, v1.y, v1.z, v1.w};
    unsigned h[8], l[8];
#pragma unroll
    for (int j = 0; j < 8; ++j) {
        h[j] = f2bf(xv[j]);
        const float r = xv[j] - bflo(h[j]);  // exact (Sterbenz)
        l[j] = f2bf(r);
    }
    hi = make_uint4(h[0] | (h[1] << 16), h[2] | (h[3] << 16),
                    h[4] | (h[5] << 16), h[6] | (h[7] << 16));
    lo = make_uint4(l[0] | (l[1] << 16), l[2] | (l[3] << 16),
                    l[4] | (l[5] << 16), l[6] | (l[7] << 16));
}

// ===========================================================================
// Weight prep: WT1_hi/lo[n][k] = split(W1[k][n]) (128x128),
//              WT2_hi/lo[n][k] = split(W2[k][n]) (64 rows x 128 k)
// ===========================================================================
__global__ __launch_bounds__(256) void k_wprep(const float* __restrict__ W1,
                                               const float* __restrict__ W2,
                                               unsigned short* __restrict__ WT1h,
                                               unsigned short* __restrict__ WT1l,
                                               unsigned short* __restrict__ WT2h,
                                               unsigned short* __restrict__ WT2l) {
    const int i = blockIdx.x * 256 + threadIdx.x;
    if (i < 16384) {
        const int nn = i & 127, k = i >> 7;
        const float v = W1[k * 128 + nn];
        const unsigned h = f2bf(v);
        const float r = v - bflo(h);
        WT1h[nn * 128 + k] = (unsigned short)h;
        WT1l[nn * 128 + k] = (unsigned short)f2bf(r);
    }
    if (i < 8192) {
        const int nn = i & 63, k = i >> 6;
        const float v = W2[k * 64 + nn];
        const unsigned h = f2bf(v);
        const float r = v - bflo(h);
        WT2h[nn * 128 + k] = (unsigned short)h;
        WT2l[nn * 128 + k] = (unsigned short)f2bf(r);
    }
}

// ===========================================================================
// CSR build. Buckets = dst>>7 (128 nodes each).
// packed edge word: (dstLocal[7b] << 25) | src[25b]   (n < 2^25)
// Global-atomic de-contention: count uses 32 replica histograms; scatter
// uses line-padded cursors (one word per 64B line) + chunked blocks so each
// cursor line sees ~#blocks atomics, not #blocks*16.
// ===========================================================================
// scan: bktBase[i] = exclusive prefix of (sum of 32 count replicas);
//       bktCurP[i*16] = same (padded allocation cursors for scatter).
__global__ __launch_bounds__(256) void k_bktscan(const int* __restrict__ bktCnt,
                                                 int* __restrict__ bktBase,
                                                 int* __restrict__ bktCurP, int NB) {
    __shared__ int sh[256];
    int carry = 0;
    for (int c0 = 0; c0 < NB; c0 += 256) {
        const int i = c0 + threadIdx.x;
        int v = 0;
        if (i < NB) {
#pragma unroll
            for (int r = 0; r < 32; ++r) v += bktCnt[r * 1024 + i];
        }
        sh[threadIdx.x] = v;
        __syncthreads();
        for (int off = 1; off < 256; off <<= 1) {
            int t = (threadIdx.x >= off) ? sh[threadIdx.x - off] : 0;
            __syncthreads();
            sh[threadIdx.x] += t;
            __syncthreads();
        }
        if (i < NB) {
            const int excl = carry + sh[threadIdx.x] - v;
            bktBase[i] = excl;
            bktCurP[i * 16] = excl;
        }
        const int tot = sh[255];
        __syncthreads();
        carry += tot;
    }
    if (threadIdx.x == 0) bktBase[NB] = carry;
}

// 2-pass streaming scatter: block handles 16384 edges. Pass 1: LDS histogram.
// Alloc: ONE global atomic per (block,bucket) on padded cursor. Pass 2:
// re-read edges, place via LDS cursors, write packed word directly.
__global__ __launch_bounds__(256) void k_bktscatter(const int* __restrict__ ei,
                                                    int* __restrict__ bktCurP,
                                                    unsigned int* __restrict__ packed,
                                                    int E, int n) {
    __shared__ int hist[1024];
    __shared__ int sCur[1024];
    for (int i = threadIdx.x; i < 1024; i += 256) hist[i] = 0;
    __syncthreads();
    const int base0 = blockIdx.x * 16384;
    const int lim = min(16384, E - base0);
    for (int off = threadIdx.x; off < lim; off += 256) {
        const int d = clampidx(ei[(size_t)E + base0 + off], n);
        atomicAdd(&hist[d >> 7], 1);
    }
    __syncthreads();
    for (int b = threadIdx.x; b < 1024; b += 256) {
        const int c = hist[b];
        sCur[b] = c ? atomicAdd(&bktCurP[b * 16], c) : 0;
    }
    __syncthreads();
    for (int off = threadIdx.x; off < lim; off += 256) {
        const int i = base0 + off;
        const int s = clampidx(ei[i], n);
        const int d = clampidx(ei[(size_t)E + i], n);
        const int pos = atomicAdd(&sCur[d >> 7], 1);
        packed[pos] = ((unsigned)(d & 127) << 25) | (unsigned)s;
    }
}

__global__ __launch_bounds__(256) void k_bktfill(const unsigned int* __restrict__ packed,
                                                 const int* __restrict__ bktBase,
                                                 int* __restrict__ p, float* __restrict__ dinv,
                                                 int* __restrict__ srcs, int n) {
    constexpr int CAP = 8192;
    __shared__ unsigned int sPack[CAP];
    __shared__ int sSrc[CAP];
    __shared__ int deg[128], incl[128], cur[128];
    const int bkt = blockIdx.x;
    const int e0 = bktBase[bkt], e1 = bktBase[bkt + 1];
    const int cnt = e1 - e0;
    const int tid = threadIdx.x;
    if (tid < 128) deg[tid] = 0;
    __syncthreads();
    for (int i = tid; i < cnt; i += 256) {
        const unsigned int u = packed[e0 + i];
        if (i < CAP) sPack[i] = u;
        atomicAdd(&deg[u >> 25], 1);
    }
    __syncthreads();
    if (tid < 128) incl[tid] = deg[tid];
    __syncthreads();
    for (int off = 1; off < 128; off <<= 1) {
        const int v = (tid < 128 && tid >= off) ? incl[tid - off] : 0;
        __syncthreads();
        if (tid < 128) incl[tid] += v;
        __syncthreads();
    }
    const int node0 = bkt << 7;
    if (tid < 128) {
        cur[tid] = incl[tid] - deg[tid];
        const int node = node0 + tid;
        if (node < n) {
            p[node] = e0 + incl[tid];
            dinv[node] = rsqrtf((float)deg[tid] + 1.0f);
        }
    }
    __syncthreads();
    for (int i = tid; i < cnt; i += 256) {
        const unsigned int u = (i < CAP) ? sPack[i] : packed[e0 + i];
        const int dl = (int)(u >> 25);
        const int s = (int)(u & 0x1FFFFFFu);
        const int pos = atomicAdd(&cur[dl], 1);
        if (pos < CAP) sSrc[pos] = s;
        else srcs[e0 + pos] = s;
    }
    __syncthreads();
    const int lim = cnt < CAP ? cnt : CAP;
    for (int i = tid; i < lim; i += 256) srcs[e0 + i] = sSrc[i];
}

// ===========================================================================
// Layer-1 GEMM via MFMA (bf16 split, 3 terms) fused with CSR bucket-count.
// Count blocks write into 32 replica histograms (contention /32).
// ===========================================================================
__global__ __launch_bounds__(256) void k_gemm1_count(
    const float* __restrict__ x, const unsigned short* __restrict__ WTh,
    const unsigned short* __restrict__ WTl, unsigned short* __restrict__ Y16, int n,
    const int* __restrict__ ei, int* __restrict__ bktCnt, int E, int nCnt) {
    __shared__ int hist[1024];
    if ((int)blockIdx.x < nCnt) {
        for (int i = threadIdx.x; i < 1024; i += 256) hist[i] = 0;
        __syncthreads();
        const int base = blockIdx.x * 4096;
#pragma unroll
        for (int j = 0; j < 16; ++j) {
            int i = base + j * 256 + threadIdx.x;
            if (i < E) atomicAdd(&hist[clampidx(ei[(size_t)E + i], n) >> 7], 1);
        }
        __syncthreads();
        int* rep = bktCnt + (blockIdx.x & 31) * 1024;
        for (int b = threadIdx.x; b < 1024; b += 256) {
            int c = hist[b];
            if (c) atomicAdd(&rep[b], c);
        }
        return;
    }
    const int blk = (int)blockIdx.x - nCnt;
    const int lane = threadIdx.x & 63;
    const int row16 = lane & 15;
    const int kg = lane >> 4;
    const int rowbase = blk * 64 + (threadIdx.x >> 6) * 16;
    const int grow = rowbase + row16;

    U8 ahi[4], alo[4];
    if (grow < n) {
        const float* xp = x + (size_t)grow * 128 + kg * 8;
#pragma unroll
        for (int k0 = 0; k0 < 4; ++k0) {
            const float4 v0 = *(const float4*)(xp + k0 * 32);
            const float4 v1 = *(const float4*)(xp + k0 * 32 + 4);
            split8(v0, v1, ahi[k0].u, alo[k0].u);
        }
    } else {
#pragma unroll
        for (int k0 = 0; k0 < 4; ++k0) {
            ahi[k0].u = make_uint4(0, 0, 0, 0);
            alo[k0].u = make_uint4(0, 0, 0, 0);
        }
    }

    f32x4 acc[8];
#pragma unroll
    for (int nt = 0; nt < 8; ++nt) acc[nt] = (f32x4){0.f, 0.f, 0.f, 0.f};

#pragma unroll
    for (int nt = 0; nt < 8; ++nt) {
        const unsigned short* bp = WTh + (size_t)(nt * 16 + row16) * 128 + kg * 8;
        const unsigned short* bq = WTl + (size_t)(nt * 16 + row16) * 128 + kg * 8;
#pragma unroll
        for (int k0 = 0; k0 < 4; ++k0) {
            U8 bh, bl;
            bh.u = *(const uint4*)(bp + k0 * 32);
            bl.u = *(const uint4*)(bq + k0 * 32);
            acc[nt] = __builtin_amdgcn_mfma_f32_16x16x32_bf16(ahi[k0].v, bh.v, acc[nt], 0, 0, 0);
            acc[nt] = __builtin_amdgcn_mfma_f32_16x16x32_bf16(alo[k0].v, bh.v, acc[nt], 0, 0, 0);
            acc[nt] = __builtin_amdgcn_mfma_f32_16x16x32_bf16(ahi[k0].v, bl.v, acc[nt], 0, 0, 0);
        }
    }

    // D layout: col = lane&15, row = (lane>>4)*4 + reg
    const int m4 = (lane >> 4) * 4;
#pragma unroll
    for (int nt = 0; nt < 8; ++nt) {
#pragma unroll
        for (int r = 0; r < 4; ++r) {
            const int orow = rowbase + m4 + r;
            if (orow < n)
                Y16[(size_t)orow * 128 + nt * 16 + row16] = (unsigned short)f2bf(acc[nt][r]);
        }
    }
}

// ===========================================================================
// Layer-2 GEMM via MFMA: Y16[n,64] = bf16( H1b[n,128](bf16) @ W2[128,64] )
// ===========================================================================
__global__ __launch_bounds__(256) void k_gemm2_mfma(const unsigned short* __restrict__ H16,
                                                    const unsigned short* __restrict__ WTh,
                                                    const unsigned short* __restrict__ WTl,
                                                    unsigned short* __restrict__ Y16, int n) {
    const int lane = threadIdx.x & 63;
    const int row16 = lane & 15;
    const int kg = lane >> 4;
    const int rowbase = blockIdx.x * 64 + (threadIdx.x >> 6) * 16;
    const int grow = rowbase + row16;

    U8 a[4];
    if (grow < n) {
        const unsigned short* ap = H16 + (size_t)grow * 128 + kg * 8;
#pragma unroll
        for (int k0 = 0; k0 < 4; ++k0) a[k0].u = *(const uint4*)(ap + k0 * 32);
    } else {
#pragma unroll
        for (int k0 = 0; k0 < 4; ++k0) a[k0].u = make_uint4(0, 0, 0, 0);
    }

    f32x4 acc[4];
#pragma unroll
    for (int nt = 0; nt < 4; ++nt) acc[nt] = (f32x4){0.f, 0.f, 0.f, 0.f};

#pragma unroll
    for (int nt = 0; nt < 4; ++nt) {
        const unsigned short* bp = WTh + (size_t)(nt * 16 + row16) * 128 + kg * 8;
        const unsigned short* bq = WTl + (size_t)(nt * 16 + row16) * 128 + kg * 8;
#pragma unroll
        for (int k0 = 0; k0 < 4; ++k0) {
            U8 bh, bl;
            bh.u = *(const uint4*)(bp + k0 * 32);
            bl.u = *(const uint4*)(bq + k0 * 32);
            acc[nt] = __builtin_amdgcn_mfma_f32_16x16x32_bf16(a[k0].v, bh.v, acc[nt], 0, 0, 0);
            acc[nt] = __builtin_amdgcn_mfma_f32_16x16x32_bf16(a[k0].v, bl.v, acc[nt], 0, 0, 0);
        }
    }

    const int m4 = (lane >> 4) * 4;
#pragma unroll
    for (int nt = 0; nt < 4; ++nt) {
#pragma unroll
        for (int r = 0; r < 4; ++r) {
            const int orow = rowbase + m4 + r;
            if (orow < n)
                Y16[(size_t)orow * 64 + nt * 16 + row16] = (unsigned short)f2bf(acc[nt][r]);
        }
    }
}

// ===========================================================================
// Layer-1 gather, scalar-pipe structure: one wave per node, 128 cols.
// ===========================================================================
__global__ __launch_bounds__(256) void k_gather128(const unsigned int* __restrict__ XW,
                                                   const int* __restrict__ p,
                                                   const int* __restrict__ srcs,
                                                   const float* __restrict__ dinv,
                                                   const float* __restrict__ b1,
                                                   unsigned int* __restrict__ H1b, int n) {
    const int node = __builtin_amdgcn_readfirstlane(blockIdx.x * 4 + (threadIdx.x >> 6));
    if (node >= n) return;
    const int t = threadIdx.x & 63;
    const int start = (node == 0) ? 0 : p[node - 1];
    const int end = p[node];
    const float din = dinv[node];
    const unsigned int us = XW[(size_t)node * 64 + t];
    float a0 = bflo(us) * din, a1 = bfhi(us) * din;

    int c = start;
    for (; c + 16 <= end; c += 16) {
        int s[16];
#pragma unroll
        for (int k = 0; k < 16; ++k) s[k] = __builtin_amdgcn_readfirstlane(srcs[c + k]);
        float w[16];
        unsigned int u[16];
#pragma unroll
        for (int k = 0; k < 16; ++k) {
            w[k] = dinv[s[k]];
            u[k] = XW[((unsigned)s[k] << 6) + t];
        }
#pragma unroll
        for (int k = 0; k < 16; ++k) {
            a0 = fmaf(bflo(u[k]), w[k], a0);
            a1 = fmaf(bfhi(u[k]), w[k], a1);
        }
    }
    for (; c + 4 <= end; c += 4) {
        int s[4];
#pragma unroll
        for (int k = 0; k < 4; ++k) s[k] = __builtin_amdgcn_readfirstlane(srcs[c + k]);
        float w[4];
        unsigned int u[4];
#pragma unroll
        for (int k = 0; k < 4; ++k) {
            w[k] = dinv[s[k]];
            u[k] = XW[((unsigned)s[k] << 6) + t];
        }
#pragma unroll
        for (int k = 0; k < 4; ++k) {
            a0 = fmaf(bflo(u[k]), w[k], a0);
            a1 = fmaf(bfhi(u[k]), w[k], a1);
        }
    }
    for (; c < end; ++c) {
        const int s = __builtin_amdgcn_readfirstlane(srcs[c]);
        const float w = dinv[s];
        const unsigned int u = XW[((unsigned)s << 6) + t];
        a0 = fmaf(bflo(u), w, a0);
        a1 = fmaf(bfhi(u), w, a1);
    }
    const float r0 = fmaxf(fmaf(a0, din, b1[2 * t]), 0.0f);
    const float r1 = fmaxf(fmaf(a1, din, b1[2 * t + 1]), 0.0f);
    H1b[(size_t)node * 64 + t] = f2bf(r0) | (f2bf(r1) << 16);
}

// ===========================================================================
// Layer-2 gather, same scalar-pipe structure: one wave per node, 64 cols.
// ===========================================================================
__global__ __launch_bounds__(256) void k_gather64(const unsigned short* __restrict__ h2,
                                                  const int* __restrict__ p,
                                                  const int* __restrict__ srcs,
                                                  const float* __restrict__ dinv,
                                                  const float* __restrict__ b2,
                                                  float* __restrict__ out, int n) {
    const int node = __builtin_amdgcn_readfirstlane(blockIdx.x * 4 + (threadIdx.x >> 6));
    if (node >= n) return;
    const int t = threadIdx.x & 63;
    const int start = (node == 0) ? 0 : p[node - 1];
    const int end = p[node];
    const float din = dinv[node];
    float acc = bflo(h2[(size_t)node * 64 + t]) * din;

    int c = start;
    for (; c + 16 <= end; c += 16) {
        int s[16];
#pragma unroll
        for (int k = 0; k < 16; ++k) s[k] = __builtin_amdgcn_readfirstlane(srcs[c + k]);
        float w[16], v[16];
#pragma unroll
        for (int k = 0; k < 16; ++k) {
            w[k] = dinv[s[k]];
            v[k] = bflo(h2[((unsigned)s[k] << 6) + t]);
        }
#pragma unroll
        for (int k = 0; k < 16; ++k) acc = fmaf(v[k], w[k], acc);
    }
    for (; c + 4 <= end; c += 4) {
        int s[4];
#pragma unroll
        for (int k = 0; k < 4; ++k) s[k] = __builtin_amdgcn_readfirstlane(srcs[c + k]);
        float w[4], v[4];
#pragma unroll
        for (int k = 0; k < 4; ++k) {
            w[k] = dinv[s[k]];
            v[k] = bflo(h2[((unsigned)s[k] << 6) + t]);
        }
#pragma unroll
        for (int k = 0; k < 4; ++k) acc = fmaf(v[k], w[k], acc);
    }
    for (; c < end; ++c) {
        const int s = __builtin_amdgcn_readfirstlane(srcs[c]);
        const float w = dinv[s];
        acc = fmaf(bflo(h2[((unsigned)s << 6) + t]), w, acc);
    }
    out[(size_t)node * 64 + t] = fmaf(acc, din, b2[t]);
}

// ===========================================================================
extern "C" void kernel_launch(void* const* d_in, const int* in_sizes, int n_in,
                              void* d_out, int out_size, void* d_ws, size_t ws_size,
                              hipStream_t stream) {
    const float* x  = (const float*)d_in[0];
    const int* ei   = (const int*)d_in[1];
    const float* W1 = (const float*)d_in[2];
    const float* b1 = (const float*)d_in[3];
    const float* W2 = (const float*)d_in[4];
    const float* b2 = (const float*)d_in[5];

    const int n = in_sizes[0] / 128;
    const int E = in_sizes[1] / 2;
    const int NB = (n + 127) >> 7;

    // ws layout: p[n] | dinv[n] | srcs[E] | XW[n*64 u32] | H1b[n*64 u32] |
    //            WT1h|WT1l (128x128 bf16) | WT2h|WT2l (64x128 bf16)
    // CSR-build temporaries alias into the H1b region (dead until gather128):
    //   pk[E] | bCnt[32*1024] | bBase[1025] | bCurP[1024*16 padded]
    auto al = [](size_t b) { return (b + 255) & ~(size_t)255; };
    const size_t off_p    = 0;
    const size_t off_dinv = off_p + al((size_t)n * 4);
    const size_t off_srcs = off_dinv + al((size_t)n * 4);
    const size_t off_XW   = off_srcs + al((size_t)E * 4);
    const size_t off_H1b  = off_XW + al((size_t)n * 64 * 4);
    const size_t off_w1h  = off_H1b + al((size_t)n * 64 * 4);
    const size_t off_w1l  = off_w1h + al(128 * 128 * 2);
    const size_t off_w2h  = off_w1l + al(128 * 128 * 2);
    const size_t off_w2l  = off_w2h + al(64 * 128 * 2);
    const size_t need     = off_w2l + (size_t)64 * 128 * 2;
    const size_t off_pk   = off_H1b;
    const size_t off_bc   = off_pk + al((size_t)E * 4);
    const size_t off_bb   = off_bc + al(32 * 1024 * 4);
    const size_t off_bu   = off_bb + al(1025 * 4);
    const size_t csr_end  = off_bu + (size_t)1024 * 16 * 4;

    if (ws_size < need || NB > 1024 || csr_end > off_w1h) {
        hipMemsetAsync(d_out, 0, (size_t)out_size * 4, stream);
        return;
    }

    int*            p    = (int*)((char*)d_ws + off_p);
    float*          dinv = (float*)((char*)d_ws + off_dinv);
    int*            srcs = (int*)((char*)d_ws + off_srcs);
    unsigned int*   XW   = (unsigned int*)((char*)d_ws + off_XW);
    unsigned int*   H1b  = (unsigned int*)((char*)d_ws + off_H1b);
    unsigned int*   pk   = (unsigned int*)((char*)d_ws + off_pk);
    int*            bCnt = (int*)((char*)d_ws + off_bc);
    int*            bBase= (int*)((char*)d_ws + off_bb);
    int*            bCurP= (int*)((char*)d_ws + off_bu);
    unsigned short* WT1h = (unsigned short*)((char*)d_ws + off_w1h);
    unsigned short* WT1l = (unsigned short*)((char*)d_ws + off_w1l);
    unsigned short* WT2h = (unsigned short*)((char*)d_ws + off_w2h);
    unsigned short* WT2l = (unsigned short*)((char*)d_ws + off_w2l);
    float*          out  = (float*)d_out;

    const int gEdge = (E + 4095) / 4096;
    const int gScat = (E + 16383) / 16384;
    const int gM    = (n + 63) / 64;
    const int gG    = (n + 3) / 4;

    // Weight transpose + bf16 hi/lo split (tiny); zero the replica histograms
    hipMemsetAsync(bCnt, 0, 32 * 1024 * 4, stream);
    k_wprep<<<64, 256, 0, stream>>>(W1, W2, WT1h, WT1l, WT2h, WT2l);

    // Fused: CSR bucket-count (blocks [0,gEdge), 32-replica) + x@W1 via MFMA
    k_gemm1_count<<<gEdge + gM, 256, 0, stream>>>(x, WT1h, WT1l, (unsigned short*)XW, n,
                                                  ei, bCnt, E, gEdge);

    // CSR build
    k_bktscan<<<1, 256, 0, stream>>>(bCnt, bBase, bCurP, NB);
    k_bktscatter<<<gScat, 256, 0, stream>>>(ei, bCurP, pk, E, n);
    k_bktfill<<<NB, 256, 0, stream>>>(pk, bBase, p, dinv, srcs, n);

    // h1 = relu(gather(XW) + b1) -> H1b (bf16)
    k_gather128<<<gG, 256, 0, stream>>>(XW, p, srcs, dinv, b1, H1b, n);

    // h2 = bf16(h1 @ W2) -> XW region via MFMA
    k_gemm2_mfma<<<gM, 256, 0, stream>>>((const unsigned short*)H1b, WT2h, WT2l,
                                         (unsigned short*)XW, n);

    // out = gather(h2) + b2 -> d_out (f32)
    k_gather64<<<gG, 256, 0, stream>>>((const unsigned short*)XW, p, srcs, dinv, b2, out, n);
}

// Round 6
// 343.852 us; speedup vs baseline: 1.1025x; 1.1025x over previous
//
#include <hip/hip_runtime.h>
#include <hip/hip_bf16.h>

#define DEVINL __device__ __forceinline__

typedef __attribute__((ext_vector_type(8))) short bf16x8;  // 8 bf16 (4 VGPR)
typedef __attribute__((ext_vector_type(4))) float f32x4;   // MFMA 16x16 accumulator

union U8 {
    bf16x8 v;
    uint4 u;
};

DEVINL int clampidx(int v, int n) { return ((unsigned)v < (unsigned)n) ? v : 0; }
DEVINL float bflo(unsigned int u) { return __uint_as_float(u << 16); }
DEVINL float bfhi(unsigned int u) { return __uint_as_float(u & 0xffff0000u); }
// f32 -> bf16 round-to-nearest-even (finite inputs only)
DEVINL unsigned int f2bf(float f) {
    unsigned int u = __float_as_uint(f);
    u += 0x7fffu + ((u >> 16) & 1u);
    return u >> 16;
}

// split 8 f32 into bf16-hi frag + bf16-lo frag (lo = exact residual, RTN)
DEVINL void split8(const float4 v0, const float4 v1, uint4& hi, uint4& lo) {
    const float xv[8] = {v0.x, v0.y, v0.z, v0.w, v1.x, v1.y, v1.z, v1.w};
    unsigned h[8], l[8];
#pragma unroll
    for (int j = 0; j < 8; ++j) {
        h[j] = f2bf(xv[j]);
        const float r = xv[j] - bflo(h[j]);  // exact (Sterbenz)
        l[j] = f2bf(r);
    }
    hi = make_uint4(h[0] | (h[1] << 16), h[2] | (h[3] << 16),
                    h[4] | (h[5] << 16), h[6] | (h[7] << 16));
    lo = make_uint4(l[0] | (l[1] << 16), l[2] | (l[3] << 16),
                    l[4] | (l[5] << 16), l[6] | (l[7] << 16));
}

// ===========================================================================
// CSR bucket-count (round-3 proven form) + weight-prep folded into blocks
// 0..63 (wprep is independent of count; consumed by later dispatches only).
// ===========================================================================
__global__ __launch_bounds__(256) void k_count_wprep(
    const int* __restrict__ ei, int* __restrict__ bktCnt, int E, int n,
    const float* __restrict__ W1, const float* __restrict__ W2,
    unsigned short* __restrict__ WT1h, unsigned short* __restrict__ WT1l,
    unsigned short* __restrict__ WT2h, unsigned short* __restrict__ WT2l) {
    __shared__ int hist[1024];
    // weight prep on first 64 blocks (16384 W1 elems, 8192 W2 elems)
    const int gi = blockIdx.x * 256 + threadIdx.x;
    if (gi < 16384) {
        const int nn = gi & 127, k = gi >> 7;
        const float v = W1[k * 128 + nn];
        const unsigned h = f2bf(v);
        const float r = v - bflo(h);
        WT1h[nn * 128 + k] = (unsigned short)h;
        WT1l[nn * 128 + k] = (unsigned short)f2bf(r);
    }
    if (gi < 8192) {
        const int nn = gi & 63, k = gi >> 6;
        const float v = W2[k * 64 + nn];
        const unsigned h = f2bf(v);
        const float r = v - bflo(h);
        WT2h[nn * 128 + k] = (unsigned short)h;
        WT2l[nn * 128 + k] = (unsigned short)f2bf(r);
    }
    // bucket count (dst>>7)
    for (int i = threadIdx.x; i < 1024; i += 256) hist[i] = 0;
    __syncthreads();
    const int base = blockIdx.x * 4096;
#pragma unroll
    for (int j = 0; j < 16; ++j) {
        int i = base + j * 256 + threadIdx.x;
        if (i < E) atomicAdd(&hist[clampidx(ei[(size_t)E + i], n) >> 7], 1);
    }
    __syncthreads();
    for (int b = threadIdx.x; b < 1024; b += 256) {
        int c = hist[b];
        if (c) atomicAdd(&bktCnt[b], c);
    }
}

// ===========================================================================
// scan (round-3 form): bktBase = exclusive prefix; bktCur = copy.
// ===========================================================================
__global__ __launch_bounds__(256) void k_bktscan(const int* __restrict__ bktCnt,
                                                 int* __restrict__ bktBase,
                                                 int* __restrict__ bktCur, int NB) {
    __shared__ int sh[256];
    int carry = 0;
    for (int c0 = 0; c0 < NB; c0 += 256) {
        const int i = c0 + threadIdx.x;
        const int v = (i < NB) ? bktCnt[i] : 0;
        sh[threadIdx.x] = v;
        __syncthreads();
        for (int off = 1; off < 256; off <<= 1) {
            int t = (threadIdx.x >= off) ? sh[threadIdx.x - off] : 0;
            __syncthreads();
            sh[threadIdx.x] += t;
            __syncthreads();
        }
        if (i < NB) {
            const int excl = carry + sh[threadIdx.x] - v;
            bktBase[i] = excl;
            bktCur[i] = excl;
        }
        const int tot = sh[255];
        __syncthreads();
        carry += tot;
    }
    if (threadIdx.x == 0) bktBase[NB] = carry;
}

// ===========================================================================
// scatter (round-3 proven form): 4096 edges/block, LDS staging, per-block
// bucket alloc via one global atomic per (block,bucket).
// ===========================================================================
__global__ __launch_bounds__(256) void k_bktscatter(const int* __restrict__ ei,
                                                    int* __restrict__ bktCur,
                                                    unsigned int* __restrict__ packed,
                                                    int E, int n) {
    __shared__ unsigned int sPack[4096];
    __shared__ unsigned short sBkt[4096];
    __shared__ int sHist[1024], sStart[1024], sLoc[1024];
    for (int i = threadIdx.x; i < 1024; i += 256) {
        sHist[i] = 0;
        sLoc[i] = 0;
    }
    __syncthreads();
    const int base = blockIdx.x * 4096;
#pragma unroll
    for (int j = 0; j < 16; ++j) {
        const int k = j * 256 + threadIdx.x;
        const int i = base + k;
        if (i < E) {
            const int s = clampidx(ei[i], n);
            const int d = clampidx(ei[(size_t)E + i], n);
            const int b = d >> 7;
            sPack[k] = ((unsigned)(d & 127) << 25) | (unsigned)s;
            sBkt[k] = (unsigned short)b;
            atomicAdd(&sHist[b], 1);
        }
    }
    __syncthreads();
    for (int b = threadIdx.x; b < 1024; b += 256) {
        const int c = sHist[b];
        sStart[b] = c ? atomicAdd(&bktCur[b], c) : 0;
    }
    __syncthreads();
#pragma unroll
    for (int j = 0; j < 16; ++j) {
        const int k = j * 256 + threadIdx.x;
        const int i = base + k;
        if (i < E) {
            const int b = sBkt[k];
            const int pos = sStart[b] + atomicAdd(&sLoc[b], 1);
            packed[pos] = sPack[k];
        }
    }
}

__global__ __launch_bounds__(256) void k_bktfill(const unsigned int* __restrict__ packed,
                                                 const int* __restrict__ bktBase,
                                                 int* __restrict__ p, float* __restrict__ dinv,
                                                 int* __restrict__ srcs, int n) {
    constexpr int CAP = 8192;
    __shared__ unsigned int sPack[CAP];
    __shared__ int sSrc[CAP];
    __shared__ int deg[128], incl[128], cur[128];
    const int bkt = blockIdx.x;
    const int e0 = bktBase[bkt], e1 = bktBase[bkt + 1];
    const int cnt = e1 - e0;
    const int tid = threadIdx.x;
    if (tid < 128) deg[tid] = 0;
    __syncthreads();
    for (int i = tid; i < cnt; i += 256) {
        const unsigned int u = packed[e0 + i];
        if (i < CAP) sPack[i] = u;
        atomicAdd(&deg[u >> 25], 1);
    }
    __syncthreads();
    if (tid < 128) incl[tid] = deg[tid];
    __syncthreads();
    for (int off = 1; off < 128; off <<= 1) {
        const int v = (tid < 128 && tid >= off) ? incl[tid - off] : 0;
        __syncthreads();
        if (tid < 128) incl[tid] += v;
        __syncthreads();
    }
    const int node0 = bkt << 7;
    if (tid < 128) {
        cur[tid] = incl[tid] - deg[tid];
        const int node = node0 + tid;
        if (node < n) {
            p[node] = e0 + incl[tid];
            dinv[node] = rsqrtf((float)deg[tid] + 1.0f);
        }
    }
    __syncthreads();
    for (int i = tid; i < cnt; i += 256) {
        const unsigned int u = (i < CAP) ? sPack[i] : packed[e0 + i];
        const int dl = (int)(u >> 25);
        const int s = (int)(u & 0x1FFFFFFu);
        const int pos = atomicAdd(&cur[dl], 1);
        if (pos < CAP) sSrc[pos] = s;
        else srcs[e0 + pos] = s;
    }
    __syncthreads();
    const int lim = cnt < CAP ? cnt : CAP;
    for (int i = tid; i < lim; i += 256) srcs[e0 + i] = sSrc[i];
}

// ===========================================================================
// Layer-1 GEMM via MFMA (bf16 split, 3 terms), STANDALONE for measurement.
// 128 rows/block (4 waves x 2 row-groups of 16): each B fragment is loaded
// once and feeds TWO row-groups' MFMAs (halves per-wave B traffic; B working
// set 64KB > 32KB L1, so B loads are L2-latency — reuse is the lever).
// ===========================================================================
__global__ __launch_bounds__(256) void k_gemm1(const float* __restrict__ x,
                                               const unsigned short* __restrict__ WTh,
                                               const unsigned short* __restrict__ WTl,
                                               unsigned short* __restrict__ Y16, int n) {
    const int lane = threadIdx.x & 63;
    const int row16 = lane & 15;
    const int kg = lane >> 4;
    const int rowbase = blockIdx.x * 128 + (threadIdx.x >> 6) * 32;

    U8 ahi[2][4], alo[2][4];
#pragma unroll
    for (int g = 0; g < 2; ++g) {
        const int grow = rowbase + g * 16 + row16;
        if (grow < n) {
            const float* xp = x + (size_t)grow * 128 + kg * 8;
#pragma unroll
            for (int k0 = 0; k0 < 4; ++k0) {
                const float4 v0 = *(const float4*)(xp + k0 * 32);
                const float4 v1 = *(const float4*)(xp + k0 * 32 + 4);
                split8(v0, v1, ahi[g][k0].u, alo[g][k0].u);
            }
        } else {
#pragma unroll
            for (int k0 = 0; k0 < 4; ++k0) {
                ahi[g][k0].u = make_uint4(0, 0, 0, 0);
                alo[g][k0].u = make_uint4(0, 0, 0, 0);
            }
        }
    }

    f32x4 acc[2][8];
#pragma unroll
    for (int g = 0; g < 2; ++g)
#pragma unroll
        for (int nt = 0; nt < 8; ++nt) acc[g][nt] = (f32x4){0.f, 0.f, 0.f, 0.f};

#pragma unroll
    for (int nt = 0; nt < 8; ++nt) {
        const unsigned short* bp = WTh + (size_t)(nt * 16 + row16) * 128 + kg * 8;
        const unsigned short* bq = WTl + (size_t)(nt * 16 + row16) * 128 + kg * 8;
#pragma unroll
        for (int k0 = 0; k0 < 4; ++k0) {
            U8 bh, bl;
            bh.u = *(const uint4*)(bp + k0 * 32);
            bl.u = *(const uint4*)(bq + k0 * 32);
            acc[0][nt] = __builtin_amdgcn_mfma_f32_16x16x32_bf16(ahi[0][k0].v, bh.v, acc[0][nt], 0, 0, 0);
            acc[0][nt] = __builtin_amdgcn_mfma_f32_16x16x32_bf16(alo[0][k0].v, bh.v, acc[0][nt], 0, 0, 0);
            acc[0][nt] = __builtin_amdgcn_mfma_f32_16x16x32_bf16(ahi[0][k0].v, bl.v, acc[0][nt], 0, 0, 0);
            acc[1][nt] = __builtin_amdgcn_mfma_f32_16x16x32_bf16(ahi[1][k0].v, bh.v, acc[1][nt], 0, 0, 0);
            acc[1][nt] = __builtin_amdgcn_mfma_f32_16x16x32_bf16(alo[1][k0].v, bh.v, acc[1][nt], 0, 0, 0);
            acc[1][nt] = __builtin_amdgcn_mfma_f32_16x16x32_bf16(ahi[1][k0].v, bl.v, acc[1][nt], 0, 0, 0);
        }
    }

    // D layout: col = lane&15, row = (lane>>4)*4 + reg
    const int m4 = (lane >> 4) * 4;
#pragma unroll
    for (int g = 0; g < 2; ++g)
#pragma unroll
        for (int nt = 0; nt < 8; ++nt) {
#pragma unroll
            for (int r = 0; r < 4; ++r) {
                const int orow = rowbase + g * 16 + m4 + r;
                if (orow < n)
                    Y16[(size_t)orow * 128 + nt * 16 + row16] =
                        (unsigned short)f2bf(acc[g][nt][r]);
            }
        }
}

// ===========================================================================
// Layer-2 GEMM via MFMA: Y16[n,64] = bf16( H1b[n,128](bf16) @ W2[128,64] )
// B working set 32KB (L1-resident) — 64-row form kept.
// ===========================================================================
__global__ __launch_bounds__(256) void k_gemm2_mfma(const unsigned short* __restrict__ H16,
                                                    const unsigned short* __restrict__ WTh,
                                                    const unsigned short* __restrict__ WTl,
                                                    unsigned short* __restrict__ Y16, int n) {
    const int lane = threadIdx.x & 63;
    const int row16 = lane & 15;
    const int kg = lane >> 4;
    const int rowbase = blockIdx.x * 64 + (threadIdx.x >> 6) * 16;
    const int grow = rowbase + row16;

    U8 a[4];
    if (grow < n) {
        const unsigned short* ap = H16 + (size_t)grow * 128 + kg * 8;
#pragma unroll
        for (int k0 = 0; k0 < 4; ++k0) a[k0].u = *(const uint4*)(ap + k0 * 32);
    } else {
#pragma unroll
        for (int k0 = 0; k0 < 4; ++k0) a[k0].u = make_uint4(0, 0, 0, 0);
    }

    f32x4 acc[4];
#pragma unroll
    for (int nt = 0; nt < 4; ++nt) acc[nt] = (f32x4){0.f, 0.f, 0.f, 0.f};

#pragma unroll
    for (int nt = 0; nt < 4; ++nt) {
        const unsigned short* bp = WTh + (size_t)(nt * 16 + row16) * 128 + kg * 8;
        const unsigned short* bq = WTl + (size_t)(nt * 16 + row16) * 128 + kg * 8;
#pragma unroll
        for (int k0 = 0; k0 < 4; ++k0) {
            U8 bh, bl;
            bh.u = *(const uint4*)(bp + k0 * 32);
            bl.u = *(const uint4*)(bq + k0 * 32);
            acc[nt] = __builtin_amdgcn_mfma_f32_16x16x32_bf16(a[k0].v, bh.v, acc[nt], 0, 0, 0);
            acc[nt] = __builtin_amdgcn_mfma_f32_16x16x32_bf16(a[k0].v, bl.v, acc[nt], 0, 0, 0);
        }
    }

    const int m4 = (lane >> 4) * 4;
#pragma unroll
    for (int nt = 0; nt < 4; ++nt) {
#pragma unroll
        for (int r = 0; r < 4; ++r) {
            const int orow = rowbase + m4 + r;
            if (orow < n)
                Y16[(size_t)orow * 64 + nt * 16 + row16] = (unsigned short)f2bf(acc[nt][r]);
        }
    }
}

// ===========================================================================
// Layer-1 gather, scalar-pipe structure: one wave per node, 128 cols.
// ===========================================================================
__global__ __launch_bounds__(256) void k_gather128(const unsigned int* __restrict__ XW,
                                                   const int* __restrict__ p,
                                                   const int* __restrict__ srcs,
                                                   const float* __restrict__ dinv,
                                                   const float* __restrict__ b1,
                                                   unsigned int* __restrict__ H1b, int n) {
    const int node = __builtin_amdgcn_readfirstlane(blockIdx.x * 4 + (threadIdx.x >> 6));
    if (node >= n) return;
    const int t = threadIdx.x & 63;
    const int start = (node == 0) ? 0 : p[node - 1];
    const int end = p[node];
    const float din = dinv[node];
    const unsigned int us = XW[(size_t)node * 64 + t];
    float a0 = bflo(us) * din, a1 = bfhi(us) * din;

    int c = start;
    for (; c + 16 <= end; c += 16) {
        int s[16];
#pragma unroll
        for (int k = 0; k < 16; ++k) s[k] = __builtin_amdgcn_readfirstlane(srcs[c + k]);
        float w[16];
        unsigned int u[16];
#pragma unroll
        for (int k = 0; k < 16; ++k) {
            w[k] = dinv[s[k]];
            u[k] = XW[((unsigned)s[k] << 6) + t];
        }
#pragma unroll
        for (int k = 0; k < 16; ++k) {
            a0 = fmaf(bflo(u[k]), w[k], a0);
            a1 = fmaf(bfhi(u[k]), w[k], a1);
        }
    }
    for (; c + 4 <= end; c += 4) {
        int s[4];
#pragma unroll
        for (int k = 0; k < 4; ++k) s[k] = __builtin_amdgcn_readfirstlane(srcs[c + k]);
        float w[4];
        unsigned int u[4];
#pragma unroll
        for (int k = 0; k < 4; ++k) {
            w[k] = dinv[s[k]];
            u[k] = XW[((unsigned)s[k] << 6) + t];
        }
#pragma unroll
        for (int k = 0; k < 4; ++k) {
            a0 = fmaf(bflo(u[k]), w[k], a0);
            a1 = fmaf(bfhi(u[k]), w[k], a1);
        }
    }
    for (; c < end; ++c) {
        const int s = __builtin_amdgcn_readfirstlane(srcs[c]);
        const float w = dinv[s];
        const unsigned int u = XW[((unsigned)s << 6) + t];
        a0 = fmaf(bflo(u), w, a0);
        a1 = fmaf(bfhi(u), w, a1);
    }
    const float r0 = fmaxf(fmaf(a0, din, b1[2 * t]), 0.0f);
    const float r1 = fmaxf(fmaf(a1, din, b1[2 * t + 1]), 0.0f);
    H1b[(size_t)node * 64 + t] = f2bf(r0) | (f2bf(r1) << 16);
}

// ===========================================================================
// Layer-2 gather, same scalar-pipe structure: one wave per node, 64 cols.
// ===========================================================================
__global__ __launch_bounds__(256) void k_gather64(const unsigned short* __restrict__ h2,
                                                  const int* __restrict__ p,
                                                  const int* __restrict__ srcs,
                                                  const float* __restrict__ dinv,
                                                  const float* __restrict__ b2,
                                                  float* __restrict__ out, int n) {
    const int node = __builtin_amdgcn_readfirstlane(blockIdx.x * 4 + (threadIdx.x >> 6));
    if (node >= n) return;
    const int t = threadIdx.x & 63;
    const int start = (node == 0) ? 0 : p[node - 1];
    const int end = p[node];
    const float din = dinv[node];
    float acc = bflo(h2[(size_t)node * 64 + t]) * din;

    int c = start;
    for (; c + 16 <= end; c += 16) {
        int s[16];
#pragma unroll
        for (int k = 0; k < 16; ++k) s[k] = __builtin_amdgcn_readfirstlane(srcs[c + k]);
        float w[16], v[16];
#pragma unroll
        for (int k = 0; k < 16; ++k) {
            w[k] = dinv[s[k]];
            v[k] = bflo(h2[((unsigned)s[k] << 6) + t]);
        }
#pragma unroll
        for (int k = 0; k < 16; ++k) acc = fmaf(v[k], w[k], acc);
    }
    for (; c + 4 <= end; c += 4) {
        int s[4];
#pragma unroll
        for (int k = 0; k < 4; ++k) s[k] = __builtin_amdgcn_readfirstlane(srcs[c + k]);
        float w[4], v[4];
#pragma unroll
        for (int k = 0; k < 4; ++k) {
            w[k] = dinv[s[k]];
            v[k] = bflo(h2[((unsigned)s[k] << 6) + t]);
        }
#pragma unroll
        for (int k = 0; k < 4; ++k) acc = fmaf(v[k], w[k], acc);
    }
    for (; c < end; ++c) {
        const int s = __builtin_amdgcn_readfirstlane(srcs[c]);
        const float w = dinv[s];
        acc = fmaf(bflo(h2[((unsigned)s << 6) + t]), w, acc);
    }
    out[(size_t)node * 64 + t] = fmaf(acc, din, b2[t]);
}

// ===========================================================================
extern "C" void kernel_launch(void* const* d_in, const int* in_sizes, int n_in,
                              void* d_out, int out_size, void* d_ws, size_t ws_size,
                              hipStream_t stream) {
    const float* x  = (const float*)d_in[0];
    const int* ei   = (const int*)d_in[1];
    const float* W1 = (const float*)d_in[2];
    const float* b1 = (const float*)d_in[3];
    const float* W2 = (const float*)d_in[4];
    const float* b2 = (const float*)d_in[5];

    const int n = in_sizes[0] / 128;
    const int E = in_sizes[1] / 2;
    const int NB = (n + 127) >> 7;

    // ws layout: p[n] | dinv[n] | srcs[E] | XW[n*64 u32] | H1b[n*64 u32] |
    //            WT1h|WT1l (128x128 bf16) | WT2h|WT2l (64x128 bf16)
    // CSR-build temporaries alias into the H1b region (dead until gather128):
    //   pk[E] | bCnt[1024] | bBase[1025] | bCur[1024]
    auto al = [](size_t b) { return (b + 255) & ~(size_t)255; };
    const size_t off_p    = 0;
    const size_t off_dinv = off_p + al((size_t)n * 4);
    const size_t off_srcs = off_dinv + al((size_t)n * 4);
    const size_t off_XW   = off_srcs + al((size_t)E * 4);
    const size_t off_H1b  = off_XW + al((size_t)n * 64 * 4);
    const size_t off_w1h  = off_H1b + al((size_t)n * 64 * 4);
    const size_t off_w1l  = off_w1h + al(128 * 128 * 2);
    const size_t off_w2h  = off_w1l + al(128 * 128 * 2);
    const size_t off_w2l  = off_w2h + al(64 * 128 * 2);
    const size_t need     = off_w2l + (size_t)64 * 128 * 2;
    const size_t off_pk   = off_H1b;
    const size_t off_bc   = off_pk + al((size_t)E * 4);
    const size_t off_bb   = off_bc + al(1024 * 4);
    const size_t off_bu   = off_bb + al(1025 * 4);
    const size_t csr_end  = off_bu + (size_t)1024 * 4;

    if (ws_size < need || NB > 1024 || csr_end > off_w1h) {
        hipMemsetAsync(d_out, 0, (size_t)out_size * 4, stream);
        return;
    }

    int*            p    = (int*)((char*)d_ws + off_p);
    float*          dinv = (float*)((char*)d_ws + off_dinv);
    int*            srcs = (int*)((char*)d_ws + off_srcs);
    unsigned int*   XW   = (unsigned int*)((char*)d_ws + off_XW);
    unsigned int*   H1b  = (unsigned int*)((char*)d_ws + off_H1b);
    unsigned int*   pk   = (unsigned int*)((char*)d_ws + off_pk);
    int*            bCnt = (int*)((char*)d_ws + off_bc);
    int*            bBase= (int*)((char*)d_ws + off_bb);
    int*            bCur = (int*)((char*)d_ws + off_bu);
    unsigned short* WT1h = (unsigned short*)((char*)d_ws + off_w1h);
    unsigned short* WT1l = (unsigned short*)((char*)d_ws + off_w1l);
    unsigned short* WT2h = (unsigned short*)((char*)d_ws + off_w2h);
    unsigned short* WT2l = (unsigned short*)((char*)d_ws + off_w2l);
    float*          out  = (float*)d_out;

    const int gEdge = (E + 4095) / 4096;
    const int gM1   = (n + 127) / 128;
    const int gM2   = (n + 63) / 64;
    const int gG    = (n + 3) / 4;

    hipMemsetAsync(bCnt, 0, 1024 * 4, stream);

    // CSR bucket-count + weight prep (fused, independent work)
    k_count_wprep<<<gEdge, 256, 0, stream>>>(ei, bCnt, E, n, W1, W2, WT1h, WT1l, WT2h, WT2l);

    // XW = bf16(x @ W1) via MFMA (standalone, B-frag reuse x2)
    k_gemm1<<<gM1, 256, 0, stream>>>(x, WT1h, WT1l, (unsigned short*)XW, n);

    // CSR build
    k_bktscan<<<1, 256, 0, stream>>>(bCnt, bBase, bCur, NB);
    k_bktscatter<<<gEdge, 256, 0, stream>>>(ei, bCur, pk, E, n);
    k_bktfill<<<NB, 256, 0, stream>>>(pk, bBase, p, dinv, srcs, n);

    // h1 = relu(gather(XW) + b1) -> H1b (bf16)
    k_gather128<<<gG, 256, 0, stream>>>(XW, p, srcs, dinv, b1, H1b, n);

    // h2 = bf16(h1 @ W2) -> XW region via MFMA
    k_gemm2_mfma<<<gM2, 256, 0, stream>>>((const unsigned short*)H1b, WT2h, WT2l,
                                          (unsigned short*)XW, n);

    // out = gather(h2) + b2 -> d_out (f32)
    k_gather64<<<gG, 256, 0, stream>>>((const unsigned short*)XW, p, srcs, dinv, b2, out, n);
}